// Round 10
// baseline (661.347 us; speedup 1.0000x reference)
//
#include <hip/hip_runtime.h>
#include <hip/hip_bf16.h>
#include <stdint.h>

#define B_ 256
#define T_ 512
#define V_ 30000
#define E_ 256
#define H_ 32

typedef float v2f __attribute__((ext_vector_type(2)));
typedef unsigned int uint2e __attribute__((ext_vector_type(2)));

#define LOG2E_F 1.44269504088896340736f

// ---------------------------------------------------------------------------
// Raw-ISA helpers
// ---------------------------------------------------------------------------
__device__ __forceinline__ float exp2_fast(float x) {      // 2^x
    float r; asm("v_exp_f32 %0, %1" : "=v"(r) : "v"(x)); return r;
}
__device__ __forceinline__ float rcp_fast(float x) {       // 1/x
    float r; asm("v_rcp_f32 %0, %1" : "=v"(r) : "v"(x)); return r;
}
// packed fp32 FMA, all-VGPR operands: acc.{lo,hi} += w.{lo,hi} * h.{lo,hi}
__device__ __forceinline__ void pk_fma(v2f& acc, v2f w, v2f h) {
    asm("v_pk_fma_f32 %0, %1, %2, %0" : "+v"(acc) : "v"(w), "v"(h));
}
// DPP lane-permute move (XOR patterns only -> direction-unambiguous)
template <int CTRL>
__device__ __forceinline__ float mdpp(float x) {
    return __int_as_float(
        __builtin_amdgcn_mov_dpp(__float_as_int(x), CTRL, 0xF, 0xF, true));
}
#define DPP_XOR1  0xB1   // quad_perm [1,0,3,2]
#define DPP_XOR2  0x4E   // quad_perm [2,3,0,1]
#define DPP_XOR3  0x1B   // quad_perm [3,2,1,0]
#define DPP_XOR7  0x141  // row_half_mirror  (i -> i^7 within 8)
#define DPP_XOR15 0x140  // row_mirror       (i -> i^15 within 16)

// x[l] + x[l^32]: permlane32_swap(x,x) yields the pair {x[l], x[l^32]} per
// lane -> sum is exact and order-free (IEEE add commutative).
__device__ __forceinline__ float xsum32(float x) {
    uint2e r = __builtin_amdgcn_permlane32_swap(
        __float_as_uint(x), __float_as_uint(x), false, false);
    return __uint_as_float(r.x) + __uint_as_float(r.y);
}
// value of x at lane (l ^ 16): exact via xor-fold of the {self,swapped} pair
__device__ __forceinline__ float swap16(float x) {
    uint2e r = __builtin_amdgcn_permlane16_swap(
        __float_as_uint(x), __float_as_uint(x), false, false);
    return __uint_as_float(r.x ^ r.y ^ __float_as_uint(x));
}

// ---------------------------------------------------------------------------
// GEMM: Out[M,192] = (A[M,K] @ Wcat[192,K]^T + bias) * gate_scale
// gate_scale folds the exp->exp2 conversion: r,z gates * -log2e ; n * +2log2e
// ---------------------------------------------------------------------------
#define GEMM_MT 64
#define GEMM_KC 32
#define GEMM_PA 68
#define GEMM_PB 196

__global__ __launch_bounds__(256) void gemm_gates(
    const float* __restrict__ A, int M, int K,
    const float* __restrict__ Wf, const float* __restrict__ Wb,
    const float* __restrict__ bihf, const float* __restrict__ bhhf,
    const float* __restrict__ bihb, const float* __restrict__ bhhb,
    float* __restrict__ Out)
{
    __shared__ float As[GEMM_KC][GEMM_PA];
    __shared__ float Bs[GEMM_KC][GEMM_PB];

    const int tid = threadIdx.x;
    const int mbase = blockIdx.x * GEMM_MT;
    const int mg = tid >> 5, ng = tid & 31;
    const int m_off = mg * 8, n_off = ng * 6;

    float acc[8][6];
    #pragma unroll
    for (int r = 0; r < 8; ++r)
        #pragma unroll
        for (int c = 0; c < 6; ++c) acc[r][c] = 0.f;

    for (int kc = 0; kc < K; kc += GEMM_KC) {
        #pragma unroll
        for (int i = 0; i < 2; ++i) {
            int fi = tid + 256 * i;
            int row = fi >> 3, cf = fi & 7;
            int m = mbase + row;
            float4 v = make_float4(0.f, 0.f, 0.f, 0.f);
            if (m < M) v = *(const float4*)&A[(size_t)m * K + kc + cf * 4];
            As[cf * 4 + 0][row] = v.x; As[cf * 4 + 1][row] = v.y;
            As[cf * 4 + 2][row] = v.z; As[cf * 4 + 3][row] = v.w;
        }
        #pragma unroll
        for (int i = 0; i < 6; ++i) {
            int fi = tid + 256 * i;
            int g = fi >> 3, cf = fi & 7;
            const float* Wsel = (g < 96) ? (Wf + (size_t)g * K)
                                         : (Wb + (size_t)(g - 96) * K);
            float4 v = *(const float4*)&Wsel[kc + cf * 4];
            Bs[cf * 4 + 0][g] = v.x; Bs[cf * 4 + 1][g] = v.y;
            Bs[cf * 4 + 2][g] = v.z; Bs[cf * 4 + 3][g] = v.w;
        }
        __syncthreads();
        #pragma unroll
        for (int k = 0; k < GEMM_KC; ++k) {
            float a[8], bb[6];
            *(float4*)&a[0] = *(const float4*)&As[k][m_off];
            *(float4*)&a[4] = *(const float4*)&As[k][m_off + 4];
            *(float2*)&bb[0] = *(const float2*)&Bs[k][n_off];
            *(float2*)&bb[2] = *(const float2*)&Bs[k][n_off + 2];
            *(float2*)&bb[4] = *(const float2*)&Bs[k][n_off + 4];
            #pragma unroll
            for (int r = 0; r < 8; ++r)
                #pragma unroll
                for (int c = 0; c < 6; ++c)
                    acc[r][c] = fmaf(a[r], bb[c], acc[r][c]);
        }
        __syncthreads();
    }

    float bias[6], gsc[6];
    #pragma unroll
    for (int c = 0; c < 6; ++c) {
        int g = n_off + c;
        int g96 = (g < 96) ? g : g - 96;
        const float* bih = (g < 96) ? bihf : bihb;
        const float* bhh = (g < 96) ? bhhf : bhhb;
        bias[c] = bih[g96] + ((g96 < 64) ? bhh[g96] : 0.f);
        gsc[c]  = (g96 < 64) ? -LOG2E_F : 2.0f * LOG2E_F;
    }
    #pragma unroll
    for (int r = 0; r < 8; ++r) {
        int m = mbase + m_off + r;
        if (m < M) {
            float* op = &Out[(size_t)m * 192 + n_off];
            #pragma unroll
            for (int c = 0; c < 6; ++c) op[c] = (acc[r][c] + bias[c]) * gsc[c];
        }
    }
}

// ---------------------------------------------------------------------------
// GRU scan, K-split layout, TWO BATCHES PER LANE (ILP over the recurrence).
// Invariant across r4/r5/r7/r8: VALU issue ~190cy/step but wall ~700cy/step
// -> ~500cy of pure dependency stall (not memory: r5; not remat: r8; not a
// few ops: r7). With ONE chain per wave the in-order SIMD has nothing to
// issue during spine stalls. Fix: lanes carry chains for batches 2bp and
// 2bp+1 of the SAME direction -> weights (48 regs) shared, chains fully
// independent, compiler interleaves them so chain B's ops fill chain A's
// stall slots. Per-step arithmetic byte-identical to r8.
// Layout per chain: rows [L,H,L,H]; lane l & l^32 compute complementary
// k-halves of unit j; seed via permlane16_swap, 15-op DPP butterfly,
// 24 pk_fma (4+4 split), permlane32 pair-sum combine, exp2/rcp gates.
// ---------------------------------------------------------------------------
template <int USE_IDS>
__global__ __launch_bounds__(64, 1)
__attribute__((amdgpu_waves_per_eu(1, 1)))
void gru_scan(
    const float* __restrict__ gi,     // [rows,192]: G0 (gather) or gi1 (direct)
    const int* __restrict__ ids,
    const int* __restrict__ mask,
    const float* __restrict__ Whh_f, const float* __restrict__ Whh_b,
    const float* __restrict__ bhh_f, const float* __restrict__ bhh_b,
    float* __restrict__ out_seq,      // [B,T,64] or nullptr
    float* __restrict__ out_fin)      // [B,64]   or nullptr
{
    const int l = threadIdx.x;
    const int i16 = l & 15;
    const int row = l >> 4;
    const int hi = row & 1;               // unit half
    const int kh = row >> 1;              // k half this lane computes
    const int j = i16 + 16 * hi;          // this lane's unit
    const bool lower = l < 32;            // lanes 0-31: j == l
    const bool self_seed = (hi == kh);    // rows 0,3 own their k-half seed
    const int dir = blockIdx.x & 1;
    const int bp = blockIdx.x >> 1;       // batch pair
    const int b0T = (2 * bp) * T_;
    const int b1T = (2 * bp + 1) * T_;

    const float* Whh = dir ? Whh_b : Whh_f;
    const float* bhh = dir ? bhh_b : bhh_f;

    const float sRZ = -LOG2E_F;
    const float sN2 = 2.0f * LOG2E_F;

    // butterfly value order: pair q holds seed[i16^M0[q]], seed[i16^M1[q]]
    const int M0[8] = {0, 2, 7, 5, 15, 13, 8, 10};
    const int M1[8] = {1, 3, 6, 4, 14, 12, 9, 11};

    v2f wR[8], wZ[8], wN[8];
    #pragma unroll
    for (int q = 0; q < 8; ++q) {
        const int c0 = kh * 16 + (i16 ^ M0[q]);
        const int c1 = kh * 16 + (i16 ^ M1[q]);
        wR[q] = (v2f){Whh[j * 32 + c0] * sRZ, Whh[j * 32 + c1] * sRZ};
        wZ[q] = (v2f){Whh[(32 + j) * 32 + c0] * sRZ,
                      Whh[(32 + j) * 32 + c1] * sRZ};
        wN[q] = (v2f){Whh[(64 + j) * 32 + c0] * sN2,
                      Whh[(64 + j) * 32 + c1] * sN2};
    }
    float bns = bhh[64 + j] * sN2;

    // PIN at init: loads cannot be sunk into the loop.
    #pragma unroll
    for (int q = 0; q < 8; ++q)
        asm volatile("" : "+v"(wR[q]), "+v"(wZ[q]), "+v"(wN[q]));
    asm volatile("" : "+v"(bns));

    const int offR = dir * 96 + j;     // offZ = offR+32, offN = offR+64

    // logical step n = 0..511 maps to time t = dir ? T-1-n : n
    auto t_of = [&](int n) { return dir ? (T_ - 1 - n) : n; };
    auto cb0 = [&](int c) { return dir ? (b0T + 510 - 2 * c) : (b0T + 2 * c); };
    auto cb1 = [&](int c) { return dir ? (b1T + 510 - 2 * c) : (b1T + 2 * c); };

    // one GRU step (shared weights captured); byte-identical math to r8
    auto step = [&](float h, float cR, float cZ, float cN, bool mm) -> float {
        const float hx = swap16(h);
        const float seed = self_seed ? h : hx;
        v2f p[8];
        p[0].x = seed;                      p[0].y = mdpp<DPP_XOR1>(seed);
        p[1].x = mdpp<DPP_XOR2>(seed);      p[1].y = mdpp<DPP_XOR3>(seed);
        p[2].x = mdpp<DPP_XOR7>(seed);      p[2].y = mdpp<DPP_XOR7>(p[0].y);
        p[3].x = mdpp<DPP_XOR7>(p[1].x);    p[3].y = mdpp<DPP_XOR7>(p[1].y);
        p[4].x = mdpp<DPP_XOR15>(seed);     p[4].y = mdpp<DPP_XOR15>(p[0].y);
        p[5].x = mdpp<DPP_XOR15>(p[1].x);   p[5].y = mdpp<DPP_XOR15>(p[1].y);
        p[6].x = mdpp<DPP_XOR15>(p[2].x);   p[6].y = mdpp<DPP_XOR15>(p[2].y);
        p[7].x = mdpp<DPP_XOR15>(p[3].x);   p[7].y = mdpp<DPP_XOR15>(p[3].y);

        v2f aR0 = {0.f, 0.f}, aZ0 = {0.f, 0.f}, aN0 = {0.f, 0.f};
        v2f aR1 = {0.f, 0.f}, aZ1 = {0.f, 0.f}, aN1 = {0.f, 0.f};
        #pragma unroll
        for (int q = 0; q < 4; ++q) {
            pk_fma(aR0, wR[q], p[q]);
            pk_fma(aZ0, wZ[q], p[q]);
            pk_fma(aN0, wN[q], p[q]);
        }
        #pragma unroll
        for (int q = 4; q < 8; ++q) {
            pk_fma(aR1, wR[q], p[q]);
            pk_fma(aZ1, wZ[q], p[q]);
            pk_fma(aN1, wN[q], p[q]);
        }
        const v2f aR = aR0 + aR1;
        const v2f aZ = aZ0 + aZ1;
        const v2f aN = aN0 + aN1;

        const float SR = xsum32(aR.x + aR.y);
        const float SZ = xsum32(aZ.x + aZ.y);
        const float SN = xsum32(aN.x + aN.y);

        const float yr  = cR + SR;
        const float yz  = cZ + SZ;
        const float hns = bns + SN;
        const float r = rcp_fast(1.0f + exp2_fast(yr));
        const float z = rcp_fast(1.0f + exp2_fast(yz));
        const float yn = fmaf(r, hns, cN);
        const float n = fmaf(-2.0f, rcp_fast(1.0f + exp2_fast(yn)), 1.0f);
        const float hnew = n + z * (h - n);      // (1-z)n + z h
        return mm ? hnew : h;                    // packed-seq freeze
    };

    // ---- prologue ----
    int mkA_c = lower ? mask[b0T + t_of(l)] : 0;
    int mkA_n = lower ? mask[b0T + t_of(32 + l)] : 0;
    int mkB_c = lower ? mask[b1T + t_of(l)] : 0;
    int mkB_n = lower ? mask[b1T + t_of(32 + l)] : 0;

    int2 pfA = make_int2(0, 0), inA = make_int2(0, 0);
    int2 pfB = make_int2(0, 0), inB = make_int2(0, 0);
    float gAR[2][2], gAZ[2][2], gAN[2][2];
    float gBR[2][2], gBZ[2][2], gBN[2][2];
    {
        int raA, rbA, raB, rbB;
        if (USE_IDS) {
            const int2 iA = *(const int2*)&ids[cb0(0)];
            const int2 iB = *(const int2*)&ids[cb1(0)];
            raA = dir ? iA.y : iA.x;  rbA = dir ? iA.x : iA.y;
            raB = dir ? iB.y : iB.x;  rbB = dir ? iB.x : iB.y;
            pfA = *(const int2*)&ids[cb0(1)];
            pfB = *(const int2*)&ids[cb1(1)];
        } else {
            raA = b0T + t_of(0);  rbA = b0T + t_of(1);
            raB = b1T + t_of(0);  rbB = b1T + t_of(1);
        }
        const float* ga = gi + (size_t)raA * 192 + offR;
        const float* gb = gi + (size_t)rbA * 192 + offR;
        gAR[0][0] = ga[0]; gAZ[0][0] = ga[32]; gAN[0][0] = ga[64];
        gAR[0][1] = gb[0]; gAZ[0][1] = gb[32]; gAN[0][1] = gb[64];
        const float* gc = gi + (size_t)raB * 192 + offR;
        const float* gd = gi + (size_t)rbB * 192 + offR;
        gBR[0][0] = gc[0]; gBZ[0][0] = gc[32]; gBN[0][0] = gc[64];
        gBR[0][1] = gd[0]; gBZ[0][1] = gd[32]; gBN[0][1] = gd[64];
    }

    float h0 = 0.f, h1 = 0.f;

    for (int seg = 0; seg < 16; ++seg) {
        // keepalive: weights stay resident (16x/kernel, off the hot path)
        #pragma unroll
        for (int q = 0; q < 8; ++q)
            asm volatile("" : "+v"(wR[q]), "+v"(wZ[q]), "+v"(wN[q]));

        const uint32_t msA = (uint32_t)__ballot(mkA_c != 0);
        const uint32_t msB = (uint32_t)__ballot(mkB_c != 0);
        mkA_c = mkA_n; mkB_c = mkB_n;
        {
            const int ms = (seg + 2 < 16) ? (seg + 2) : 15;
            mkA_n = lower ? mask[b0T + t_of(32 * ms + l)] : 0;
            mkB_n = lower ? mask[b1T + t_of(32 * ms + l)] : 0;
        }

        for (int ch2 = 0; ch2 < 8; ++ch2) {
            const int cc0 = seg * 16 + 2 * ch2;
            #pragma unroll
            for (int pb = 0; pb < 2; ++pb) {     // two chunks: banks 0,1
                const int cc = cc0 + pb;
                // ids prefetch for chunk cc+2 (consumed next chunk)
                if (USE_IDS) {
                    const int ci = (cc + 2 < 256) ? (cc + 2) : 255;
                    inA = *(const int2*)&ids[cb0(ci)];
                    inB = *(const int2*)&ids[cb1(ci)];
                }
                // gi prefetch for chunk cc+1 -> bank pb^1, both chains
                {
                    int raA, rbA, raB, rbB;
                    if (USE_IDS) {
                        raA = dir ? pfA.y : pfA.x;  rbA = dir ? pfA.x : pfA.y;
                        raB = dir ? pfB.y : pfB.x;  rbB = dir ? pfB.x : pfB.y;
                    } else {
                        const int cg = (cc + 1 < 256) ? (cc + 1) : 255;
                        raA = b0T + t_of(2 * cg);  rbA = b0T + t_of(2 * cg + 1);
                        raB = b1T + t_of(2 * cg);  rbB = b1T + t_of(2 * cg + 1);
                    }
                    const float* ga = gi + (size_t)raA * 192 + offR;
                    const float* gb = gi + (size_t)rbA * 192 + offR;
                    gAR[pb ^ 1][0] = ga[0]; gAZ[pb ^ 1][0] = ga[32]; gAN[pb ^ 1][0] = ga[64];
                    gAR[pb ^ 1][1] = gb[0]; gAZ[pb ^ 1][1] = gb[32]; gAN[pb ^ 1][1] = gb[64];
                    const float* gc = gi + (size_t)raB * 192 + offR;
                    const float* gd = gi + (size_t)rbB * 192 + offR;
                    gBR[pb ^ 1][0] = gc[0]; gBZ[pb ^ 1][0] = gc[32]; gBN[pb ^ 1][0] = gc[64];
                    gBR[pb ^ 1][1] = gd[0]; gBZ[pb ^ 1][1] = gd[32]; gBN[pb ^ 1][1] = gd[64];
                }

                #pragma unroll
                for (int u = 0; u < 2; ++u) {
                    const int su = 4 * ch2 + 2 * pb + u;   // step within segment

                    // two independent chains; scheduler interleaves them
                    const float nh0 = step(h0, gAR[pb][u], gAZ[pb][u],
                                           gAN[pb][u], (msA >> su) & 1u);
                    const float nh1 = step(h1, gBR[pb][u], gBZ[pb][u],
                                           gBN[pb][u], (msB >> su) & 1u);
                    h0 = nh0;
                    h1 = nh1;

                    if (out_seq != nullptr && lower) {
                        const int t = t_of(32 * seg + su);
                        out_seq[(size_t)(b0T + t) * 64 + dir * 32 + j] = h0;
                        out_seq[(size_t)(b1T + t) * 64 + dir * 32 + j] = h1;
                    }
                }
                if (USE_IDS) { pfA = inA; pfB = inB; }   // rotate
            }
        }
    }

    if (out_fin != nullptr && lower) {
        out_fin[(b0T / T_) * 64 + dir * 32 + j] = h0;
        out_fin[(b1T / T_) * 64 + dir * 32 + j] = h1;
    }
}

// ---------------------------------------------------------------------------
// Head: out[b,o] = hfin[b,:] . Wout[o,:] + bout[o]
// ---------------------------------------------------------------------------
__global__ void head_kernel(const float* __restrict__ hfin,
                            const float* __restrict__ Wout,
                            const float* __restrict__ bout,
                            float* __restrict__ out)
{
    int idx = blockIdx.x * blockDim.x + threadIdx.x;
    if (idx >= B_ * 6) return;
    int b = idx / 6, o = idx % 6;
    float acc = bout[o];
    const float* hp = hfin + b * 64;
    const float* wp = Wout + o * 64;
    #pragma unroll
    for (int k = 0; k < 64; ++k) acc = fmaf(hp[k], wp[k], acc);
    out[idx] = acc;
}

// ---------------------------------------------------------------------------
extern "C" void kernel_launch(void* const* d_in, const int* in_sizes, int n_in,
                              void* d_out, int out_size, void* d_ws, size_t ws_size,
                              hipStream_t stream)
{
    const int*   ids   = (const int*)d_in[0];
    const int*   mask  = (const int*)d_in[1];
    const float* embed = (const float*)d_in[2];
    const float* Wih0f = (const float*)d_in[3];
    const float* Whh0f = (const float*)d_in[4];
    const float* bih0f = (const float*)d_in[5];
    const float* bhh0f = (const float*)d_in[6];
    const float* Wih0b = (const float*)d_in[7];
    const float* Whh0b = (const float*)d_in[8];
    const float* bih0b = (const float*)d_in[9];
    const float* bhh0b = (const float*)d_in[10];
    const float* Wih1f = (const float*)d_in[11];
    const float* Whh1f = (const float*)d_in[12];
    const float* bih1f = (const float*)d_in[13];
    const float* bhh1f = (const float*)d_in[14];
    const float* Wih1b = (const float*)d_in[15];
    const float* Whh1b = (const float*)d_in[16];
    const float* bih1b = (const float*)d_in[17];
    const float* bhh1b = (const float*)d_in[18];
    const float* Wout  = (const float*)d_in[19];
    const float* bout  = (const float*)d_in[20];

    // workspace layout (floats):
    //   gbuf : G0 [V,192] (K1,K2) then gi1 [B*T,192] (K3,K4)
    //   x1   : [B,T,64]
    //   hfin : [B,64]
    float* ws   = (float*)d_ws;
    float* gbuf = ws;
    float* x1   = ws + (size_t)B_ * T_ * 192;
    float* hfin = x1 + (size_t)B_ * T_ * 64;

    // K1: vocab-factored layer-0 input gates  G0 = (embed @ Wcat0^T + b) * gsc
    gemm_gates<<<(V_ + GEMM_MT - 1) / GEMM_MT, 256, 0, stream>>>(
        embed, V_, E_, Wih0f, Wih0b, bih0f, bhh0f, bih0b, bhh0b, gbuf);

    // K2: layer-0 bidirectional scan (gathers G0[id]), writes x1
    //     one wave per (batch-PAIR, direction): B_ blocks
    gru_scan<1><<<B_, 64, 0, stream>>>(
        gbuf, ids, mask, Whh0f, Whh0b, bhh0f, bhh0b, x1, nullptr);

    // K3: layer-1 input gates  gi1 = (x1 @ Wcat1^T + b) * gsc
    gemm_gates<<<(B_ * T_) / GEMM_MT, 256, 0, stream>>>(
        x1, B_ * T_, 64, Wih1f, Wih1b, bih1f, bhh1f, bih1b, bhh1b, gbuf);

    // K4: layer-1 scan, final hiddens only
    gru_scan<0><<<B_, 64, 0, stream>>>(
        gbuf, nullptr, mask, Whh1f, Whh1b, bhh1f, bhh1b, nullptr, hfin);

    // K5: output head
    head_kernel<<<(B_ * 6 + 255) / 256, 256, 0, stream>>>(hfin, Wout, bout,
                                                          (float*)d_out);
}

// Round 11
// 552.861 us; speedup vs baseline: 1.1962x; 1.1962x over previous
//
#include <hip/hip_runtime.h>
#include <hip/hip_bf16.h>
#include <stdint.h>

#define B_ 256
#define T_ 512
#define V_ 30000
#define E_ 256
#define H_ 32

typedef float v2f __attribute__((ext_vector_type(2)));
typedef unsigned int uint2e __attribute__((ext_vector_type(2)));

#define LOG2E_F 1.44269504088896340736f

// ---------------------------------------------------------------------------
// Raw-ISA helpers
// ---------------------------------------------------------------------------
__device__ __forceinline__ float exp2_fast(float x) {      // 2^x
    float r; asm("v_exp_f32 %0, %1" : "=v"(r) : "v"(x)); return r;
}
__device__ __forceinline__ float rcp_fast(float x) {       // 1/x
    float r; asm("v_rcp_f32 %0, %1" : "=v"(r) : "v"(x)); return r;
}
// packed fp32 FMA, all-VGPR operands: acc.{lo,hi} += w.{lo,hi} * h.{lo,hi}
__device__ __forceinline__ void pk_fma(v2f& acc, v2f w, v2f h) {
    asm("v_pk_fma_f32 %0, %1, %2, %0" : "+v"(acc) : "v"(w), "v"(h));
}
// x[l] + x[l^32]: permlane32_swap(x,x) yields the pair {x[l], x[l^32]} per
// lane -> sum is exact and lane-deterministic (IEEE add commutative).
__device__ __forceinline__ float xsum32(float x) {
    uint2e r = __builtin_amdgcn_permlane32_swap(
        __float_as_uint(x), __float_as_uint(x), false, false);
    return __uint_as_float(r.x) + __uint_as_float(r.y);
}
// x[l] + x[l^16] via permlane16_swap pair-sum (same construction)
__device__ __forceinline__ float xsum16(float x) {
    uint2e r = __builtin_amdgcn_permlane16_swap(
        __float_as_uint(x), __float_as_uint(x), false, false);
    return __uint_as_float(r.x) + __uint_as_float(r.y);
}

// ---------------------------------------------------------------------------
// GEMM: Out[M,192] = (A[M,K] @ Wcat[192,K]^T + bias) * gate_scale
// gate_scale folds the exp->exp2 conversion: r,z gates * -log2e ; n * +2log2e
// ---------------------------------------------------------------------------
#define GEMM_MT 64
#define GEMM_KC 32
#define GEMM_PA 68
#define GEMM_PB 196

__global__ __launch_bounds__(256) void gemm_gates(
    const float* __restrict__ A, int M, int K,
    const float* __restrict__ Wf, const float* __restrict__ Wb,
    const float* __restrict__ bihf, const float* __restrict__ bhhf,
    const float* __restrict__ bihb, const float* __restrict__ bhhb,
    float* __restrict__ Out)
{
    __shared__ float As[GEMM_KC][GEMM_PA];
    __shared__ float Bs[GEMM_KC][GEMM_PB];

    const int tid = threadIdx.x;
    const int mbase = blockIdx.x * GEMM_MT;
    const int mg = tid >> 5, ng = tid & 31;
    const int m_off = mg * 8, n_off = ng * 6;

    float acc[8][6];
    #pragma unroll
    for (int r = 0; r < 8; ++r)
        #pragma unroll
        for (int c = 0; c < 6; ++c) acc[r][c] = 0.f;

    for (int kc = 0; kc < K; kc += GEMM_KC) {
        #pragma unroll
        for (int i = 0; i < 2; ++i) {
            int fi = tid + 256 * i;
            int row = fi >> 3, cf = fi & 7;
            int m = mbase + row;
            float4 v = make_float4(0.f, 0.f, 0.f, 0.f);
            if (m < M) v = *(const float4*)&A[(size_t)m * K + kc + cf * 4];
            As[cf * 4 + 0][row] = v.x; As[cf * 4 + 1][row] = v.y;
            As[cf * 4 + 2][row] = v.z; As[cf * 4 + 3][row] = v.w;
        }
        #pragma unroll
        for (int i = 0; i < 6; ++i) {
            int fi = tid + 256 * i;
            int g = fi >> 3, cf = fi & 7;
            const float* Wsel = (g < 96) ? (Wf + (size_t)g * K)
                                         : (Wb + (size_t)(g - 96) * K);
            float4 v = *(const float4*)&Wsel[kc + cf * 4];
            Bs[cf * 4 + 0][g] = v.x; Bs[cf * 4 + 1][g] = v.y;
            Bs[cf * 4 + 2][g] = v.z; Bs[cf * 4 + 3][g] = v.w;
        }
        __syncthreads();
        #pragma unroll
        for (int k = 0; k < GEMM_KC; ++k) {
            float a[8], bb[6];
            *(float4*)&a[0] = *(const float4*)&As[k][m_off];
            *(float4*)&a[4] = *(const float4*)&As[k][m_off + 4];
            *(float2*)&bb[0] = *(const float2*)&Bs[k][n_off];
            *(float2*)&bb[2] = *(const float2*)&Bs[k][n_off + 2];
            *(float2*)&bb[4] = *(const float2*)&Bs[k][n_off + 4];
            #pragma unroll
            for (int r = 0; r < 8; ++r)
                #pragma unroll
                for (int c = 0; c < 6; ++c)
                    acc[r][c] = fmaf(a[r], bb[c], acc[r][c]);
        }
        __syncthreads();
    }

    float bias[6], gsc[6];
    #pragma unroll
    for (int c = 0; c < 6; ++c) {
        int g = n_off + c;
        int g96 = (g < 96) ? g : g - 96;
        const float* bih = (g < 96) ? bihf : bihb;
        const float* bhh = (g < 96) ? bhhf : bhhb;
        bias[c] = bih[g96] + ((g96 < 64) ? bhh[g96] : 0.f);
        gsc[c]  = (g96 < 64) ? -LOG2E_F : 2.0f * LOG2E_F;
    }
    #pragma unroll
    for (int r = 0; r < 8; ++r) {
        int m = mbase + m_off + r;
        if (m < M) {
            float* op = &Out[(size_t)m * 192 + n_off];
            #pragma unroll
            for (int c = 0; c < 6; ++c) op[c] = (acc[r][c] + bias[c]) * gsc[c];
        }
    }
}

// ---------------------------------------------------------------------------
// GRU scan — 2-WAVE COOPERATIVE workgroup per (batch, direction).
// r10's dual-chain test killed the latency model: wall tracks INSTRUCTION
// COUNT (~7.5 assumed-cy/instr across r0..r10). So: fewer instrs/wave-step
// + more waves. Wave w owns units [16w,16w+16); its 64 lanes = 16 units x
// 4 k-quarters -> matvec 12 pk_fma (was 24). h broadcast via double-buffered
// LDS hsh[2][32] (1 write + 2 ds_read_b128, natural k order — replaces the
// 18-instr DPP butterfly). Cross-kq combine: exact pair-sums xsum32+xsum16.
// All 4 kq-lanes of a unit compute IDENTICAL h (deterministic), so their
// same-address LDS write is an identical-value benign race (no guard).
// One __syncthreads per step; hsh parity u flips read/write buffers.
// Gate math byte-identical ordering to r8's tail (exp2/rcp, log2e folded).
// ---------------------------------------------------------------------------
template <int USE_IDS>
__global__ __launch_bounds__(128, 1)
void gru_scan(
    const float* __restrict__ gi,     // [rows,192]: G0 (gather) or gi1 (direct)
    const int* __restrict__ ids,
    const int* __restrict__ mask,
    const float* __restrict__ Whh_f, const float* __restrict__ Whh_b,
    const float* __restrict__ bhh_f, const float* __restrict__ bhh_b,
    float* __restrict__ out_seq,      // [B,T,64] or nullptr
    float* __restrict__ out_fin)      // [B,64]   or nullptr
{
    __shared__ float hsh[2][32];

    const int tid = threadIdx.x;
    const int w = tid >> 6;               // wave: units 16w..16w+15
    const int l = tid & 63;
    const int i16 = l & 15;
    const int kq = l >> 4;                // k-quarter: k in [8kq, 8kq+8)
    const int j = w * 16 + i16;           // this lane's unit
    const bool lead = (kq == 0);
    const bool lower = l < 32;
    const int dir = blockIdx.x & 1;
    const int b = blockIdx.x >> 1;
    const int bT = b * T_;

    const float* Whh = dir ? Whh_b : Whh_f;
    const float* bhh = dir ? bhh_b : bhh_f;

    const float sRZ = -LOG2E_F;
    const float sN2 = 2.0f * LOG2E_F;

    // per-lane weights: 3 gates x 8 k-values (natural order) = 12 v2f
    v2f wR[4], wZ[4], wN[4];
    #pragma unroll
    for (int q = 0; q < 4; ++q) {
        const int k0 = 8 * kq + 2 * q;
        wR[q] = (v2f){Whh[j * 32 + k0] * sRZ, Whh[j * 32 + k0 + 1] * sRZ};
        wZ[q] = (v2f){Whh[(32 + j) * 32 + k0] * sRZ,
                      Whh[(32 + j) * 32 + k0 + 1] * sRZ};
        wN[q] = (v2f){Whh[(64 + j) * 32 + k0] * sN2,
                      Whh[(64 + j) * 32 + k0 + 1] * sN2};
    }
    float bns = bhh[64 + j] * sN2;

    // PIN at init: loads cannot be sunk into the loop.
    #pragma unroll
    for (int q = 0; q < 4; ++q)
        asm volatile("" : "+v"(wR[q]), "+v"(wZ[q]), "+v"(wN[q]));
    asm volatile("" : "+v"(bns));

    const int offR = dir * 96 + j;     // offZ = offR+32, offN = offR+64

    // logical step n = 0..511 maps to time t = dir ? T-1-n : n
    auto t_of = [&](int n) { return dir ? (T_ - 1 - n) : n; };
    auto cbase = [&](int c) { return dir ? (bT + 510 - 2 * c) : (bT + 2 * c); };

    // seed h = 0 for step 0 (buffer 0)
    if (tid < 32) { hsh[0][tid] = 0.f; hsh[1][tid] = 0.f; }

    // ---- prologue (same structure as r8; per-wave duplicated loads OK) ----
    int mk_cur = lower ? mask[bT + t_of(l)] : 0;
    int mk_nxt = lower ? mask[bT + t_of(32 + l)] : 0;

    int2 ids_pf = make_int2(0, 0), ids_in = make_int2(0, 0);
    float gR[2][2], gZ[2][2], gN[2][2];
    {
        int ra, rb;
        if (USE_IDS) {
            const int2 i0 = *(const int2*)&ids[cbase(0)];
            ra = dir ? i0.y : i0.x;
            rb = dir ? i0.x : i0.y;
            ids_pf = *(const int2*)&ids[cbase(1)];
        } else {
            ra = bT + t_of(0);
            rb = bT + t_of(1);
        }
        const float* ga = gi + (size_t)ra * 192 + offR;
        const float* gb = gi + (size_t)rb * 192 + offR;
        gR[0][0] = ga[0]; gZ[0][0] = ga[32]; gN[0][0] = ga[64];
        gR[0][1] = gb[0]; gZ[0][1] = gb[32]; gN[0][1] = gb[64];
    }

    float h = 0.f;
    __syncthreads();   // hsh[0] seeded

    for (int seg = 0; seg < 16; ++seg) {
        // keepalive: weights stay resident (16x/kernel, off the hot path)
        #pragma unroll
        for (int q = 0; q < 4; ++q)
            asm volatile("" : "+v"(wR[q]), "+v"(wZ[q]), "+v"(wN[q]));

        const uint32_t mseg = (uint32_t)__ballot(mk_cur != 0);
        mk_cur = mk_nxt;
        {
            const int ms = (seg + 2 < 16) ? (seg + 2) : 15;
            mk_nxt = lower ? mask[bT + t_of(32 * ms + l)] : 0;
        }

        for (int ch2 = 0; ch2 < 8; ++ch2) {
            const int cc0 = seg * 16 + 2 * ch2;
            #pragma unroll
            for (int pb = 0; pb < 2; ++pb) {     // two 2-step chunks
                const int cc = cc0 + pb;
                if (USE_IDS) {
                    const int ci = (cc + 2 < 256) ? (cc + 2) : 255;
                    ids_in = *(const int2*)&ids[cbase(ci)];
                }
                // gi prefetch for chunk cc+1 -> bank pb^1
                {
                    int ra, rb;
                    if (USE_IDS) {
                        ra = dir ? ids_pf.y : ids_pf.x;
                        rb = dir ? ids_pf.x : ids_pf.y;
                    } else {
                        const int cg = (cc + 1 < 256) ? (cc + 1) : 255;
                        ra = bT + t_of(2 * cg);
                        rb = bT + t_of(2 * cg + 1);
                    }
                    const float* ga = gi + (size_t)ra * 192 + offR;
                    const float* gb = gi + (size_t)rb * 192 + offR;
                    gR[pb ^ 1][0] = ga[0]; gZ[pb ^ 1][0] = ga[32]; gN[pb ^ 1][0] = ga[64];
                    gR[pb ^ 1][1] = gb[0]; gZ[pb ^ 1][1] = gb[32]; gN[pb ^ 1][1] = gb[64];
                }

                #pragma unroll
                for (int u = 0; u < 2; ++u) {
                    const int su = 4 * ch2 + 2 * pb + u;   // step within segment
                    // step parity == u: read hsh[u], write hsh[u^1]

                    // seeds: this lane's k-quarter, natural order (broadcast
                    // reads: 4 distinct 32B-spaced addrs -> conflict-free)
                    const float4 s0 = *(const float4*)&hsh[u][8 * kq];
                    const float4 s1 = *(const float4*)&hsh[u][8 * kq + 4];
                    const v2f p0 = (v2f){s0.x, s0.y};
                    const v2f p1 = (v2f){s0.z, s0.w};
                    const v2f p2 = (v2f){s1.x, s1.y};
                    const v2f p3 = (v2f){s1.z, s1.w};

                    // quarter-K matvec: 3 gates x depth-4 pk_fma
                    v2f aR = {0.f, 0.f}, aZ = {0.f, 0.f}, aN = {0.f, 0.f};
                    pk_fma(aR, wR[0], p0); pk_fma(aZ, wZ[0], p0); pk_fma(aN, wN[0], p0);
                    pk_fma(aR, wR[1], p1); pk_fma(aZ, wZ[1], p1); pk_fma(aN, wN[1], p1);
                    pk_fma(aR, wR[2], p2); pk_fma(aZ, wZ[2], p2); pk_fma(aN, wN[2], p2);
                    pk_fma(aR, wR[3], p3); pk_fma(aZ, wZ[3], p3); pk_fma(aN, wN[3], p3);

                    // combine 4 k-quarters (lanes l, l^16, l^32, l^48):
                    // identical deterministic value on all 4 lanes of a unit
                    const float SR = xsum16(xsum32(aR.x + aR.y));
                    const float SZ = xsum16(xsum32(aZ.x + aZ.y));
                    const float SN = xsum16(xsum32(aN.x + aN.y));

                    const float yr  = gR[pb][u] + SR;
                    const float yz  = gZ[pb][u] + SZ;
                    const float hns = bns + SN;
                    const float r = rcp_fast(1.0f + exp2_fast(yr));
                    const float z = rcp_fast(1.0f + exp2_fast(yz));
                    const float yn = fmaf(r, hns, gN[pb][u]);
                    const float n = fmaf(-2.0f, rcp_fast(1.0f + exp2_fast(yn)), 1.0f);
                    const float hnew = n + z * (h - n);      // (1-z)n + z h
                    const bool mm = (mseg >> su) & 1u;
                    h = mm ? hnew : h;                       // packed-seq freeze

                    // publish h for next step: all 4 kq-lanes write the SAME
                    // value to the same address (identical-value benign race)
                    hsh[u ^ 1][j] = h;
                    __syncthreads();

                    if (out_seq != nullptr && lead) {
                        const int t = t_of(32 * seg + su);
                        out_seq[(size_t)(bT + t) * 64 + dir * 32 + j] = h;
                    }
                }
                if (USE_IDS) ids_pf = ids_in;   // rotate (1-chunk distance)
            }
        }
    }

    if (out_fin != nullptr && lead)
        out_fin[b * 64 + dir * 32 + j] = h;
}

// ---------------------------------------------------------------------------
// Head: out[b,o] = hfin[b,:] . Wout[o,:] + bout[o]
// ---------------------------------------------------------------------------
__global__ void head_kernel(const float* __restrict__ hfin,
                            const float* __restrict__ Wout,
                            const float* __restrict__ bout,
                            float* __restrict__ out)
{
    int idx = blockIdx.x * blockDim.x + threadIdx.x;
    if (idx >= B_ * 6) return;
    int b = idx / 6, o = idx % 6;
    float acc = bout[o];
    const float* hp = hfin + b * 64;
    const float* wp = Wout + o * 64;
    #pragma unroll
    for (int k = 0; k < 64; ++k) acc = fmaf(hp[k], wp[k], acc);
    out[idx] = acc;
}

// ---------------------------------------------------------------------------
extern "C" void kernel_launch(void* const* d_in, const int* in_sizes, int n_in,
                              void* d_out, int out_size, void* d_ws, size_t ws_size,
                              hipStream_t stream)
{
    const int*   ids   = (const int*)d_in[0];
    const int*   mask  = (const int*)d_in[1];
    const float* embed = (const float*)d_in[2];
    const float* Wih0f = (const float*)d_in[3];
    const float* Whh0f = (const float*)d_in[4];
    const float* bih0f = (const float*)d_in[5];
    const float* bhh0f = (const float*)d_in[6];
    const float* Wih0b = (const float*)d_in[7];
    const float* Whh0b = (const float*)d_in[8];
    const float* bih0b = (const float*)d_in[9];
    const float* bhh0b = (const float*)d_in[10];
    const float* Wih1f = (const float*)d_in[11];
    const float* Whh1f = (const float*)d_in[12];
    const float* bih1f = (const float*)d_in[13];
    const float* bhh1f = (const float*)d_in[14];
    const float* Wih1b = (const float*)d_in[15];
    const float* Whh1b = (const float*)d_in[16];
    const float* bih1b = (const float*)d_in[17];
    const float* bhh1b = (const float*)d_in[18];
    const float* Wout  = (const float*)d_in[19];
    const float* bout  = (const float*)d_in[20];

    // workspace layout (floats):
    //   gbuf : G0 [V,192] (K1,K2) then gi1 [B*T,192] (K3,K4)
    //   x1   : [B,T,64]
    //   hfin : [B,64]
    float* ws   = (float*)d_ws;
    float* gbuf = ws;
    float* x1   = ws + (size_t)B_ * T_ * 192;
    float* hfin = x1 + (size_t)B_ * T_ * 64;

    // K1: vocab-factored layer-0 input gates  G0 = (embed @ Wcat0^T + b) * gsc
    gemm_gates<<<(V_ + GEMM_MT - 1) / GEMM_MT, 256, 0, stream>>>(
        embed, V_, E_, Wih0f, Wih0b, bih0f, bhh0f, bih0b, bhh0b, gbuf);

    // K2: layer-0 bidirectional scan (gathers G0[id]), writes x1
    //     one 2-wave workgroup per (batch, direction)
    gru_scan<1><<<2 * B_, 128, 0, stream>>>(
        gbuf, ids, mask, Whh0f, Whh0b, bhh0f, bhh0b, x1, nullptr);

    // K3: layer-1 input gates  gi1 = (x1 @ Wcat1^T + b) * gsc
    gemm_gates<<<(B_ * T_) / GEMM_MT, 256, 0, stream>>>(
        x1, B_ * T_, 64, Wih1f, Wih1b, bih1f, bhh1f, bih1b, bhh1b, gbuf);

    // K4: layer-1 scan, final hiddens only
    gru_scan<0><<<2 * B_, 128, 0, stream>>>(
        gbuf, nullptr, mask, Whh1f, Whh1b, bhh1f, bhh1b, nullptr, hfin);

    // K5: output head
    head_kernel<<<(B_ * 6 + 255) / 256, 256, 0, stream>>>(hfin, Wout, bout,
                                                          (float*)d_out);
}

// Round 12
// 464.378 us; speedup vs baseline: 1.4242x; 1.1905x over previous
//
#include <hip/hip_runtime.h>
#include <hip/hip_bf16.h>
#include <stdint.h>

#define B_ 256
#define T_ 512
#define V_ 30000
#define E_ 256
#define H_ 32

typedef float v2f __attribute__((ext_vector_type(2)));
typedef unsigned int uint2e __attribute__((ext_vector_type(2)));

#define LOG2E_F 1.44269504088896340736f

// ---------------------------------------------------------------------------
// Raw-ISA helpers
// ---------------------------------------------------------------------------
__device__ __forceinline__ float exp2_fast(float x) {      // 2^x
    float r; asm("v_exp_f32 %0, %1" : "=v"(r) : "v"(x)); return r;
}
__device__ __forceinline__ float rcp_fast(float x) {       // 1/x
    float r; asm("v_rcp_f32 %0, %1" : "=v"(r) : "v"(x)); return r;
}
// packed fp32 FMA, all-VGPR operands: acc.{lo,hi} += w.{lo,hi} * h.{lo,hi}
__device__ __forceinline__ void pk_fma(v2f& acc, v2f w, v2f h) {
    asm("v_pk_fma_f32 %0, %1, %2, %0" : "+v"(acc) : "v"(w), "v"(h));
}
// DPP lane-permute move (XOR patterns only -> direction-unambiguous)
template <int CTRL>
__device__ __forceinline__ float mdpp(float x) {
    return __int_as_float(
        __builtin_amdgcn_mov_dpp(__float_as_int(x), CTRL, 0xF, 0xF, true));
}
#define DPP_XOR1  0xB1   // quad_perm [1,0,3,2]
#define DPP_XOR2  0x4E   // quad_perm [2,3,0,1]
#define DPP_XOR3  0x1B   // quad_perm [3,2,1,0]
#define DPP_XOR7  0x141  // row_half_mirror  (i -> i^7 within 8)
#define DPP_XOR15 0x140  // row_mirror       (i -> i^15 within 16)

// x[l] + x[l^32]: permlane32_swap(x,x) yields the pair {x[l], x[l^32]} per
// lane -> sum is exact and order-free (IEEE add commutative).
__device__ __forceinline__ float xsum32(float x) {
    uint2e r = __builtin_amdgcn_permlane32_swap(
        __float_as_uint(x), __float_as_uint(x), false, false);
    return __uint_as_float(r.x) + __uint_as_float(r.y);
}
// value of x at lane (l ^ 16): exact via xor-fold of the {self,swapped} pair
__device__ __forceinline__ float swap16(float x) {
    uint2e r = __builtin_amdgcn_permlane16_swap(
        __float_as_uint(x), __float_as_uint(x), false, false);
    return __uint_as_float(r.x ^ r.y ^ __float_as_uint(x));
}

// ---------------------------------------------------------------------------
// GEMM: Out[M,192] = (A[M,K] @ Wcat[192,K]^T + bias) * gate_scale
// gate_scale folds the exp->exp2 conversion: r,z gates * -log2e ; n * +2log2e
// r12: inner loop packed — accumulators paired over adjacent ROWS into
// v_pk_fma_f32 (A pairs are naturally aligned in LDS; B splat folds via
// op_sel). 48 fmaf -> 24 pk_fma per k per thread. Each (row,col) chain
// keeps the identical k-order -> bit-identical results.
// ---------------------------------------------------------------------------
#define GEMM_MT 64
#define GEMM_KC 32
#define GEMM_PA 68
#define GEMM_PB 196

__global__ __launch_bounds__(256) void gemm_gates(
    const float* __restrict__ A, int M, int K,
    const float* __restrict__ Wf, const float* __restrict__ Wb,
    const float* __restrict__ bihf, const float* __restrict__ bhhf,
    const float* __restrict__ bihb, const float* __restrict__ bhhb,
    float* __restrict__ Out)
{
    __shared__ float As[GEMM_KC][GEMM_PA];
    __shared__ float Bs[GEMM_KC][GEMM_PB];

    const int tid = threadIdx.x;
    const int mbase = blockIdx.x * GEMM_MT;
    const int mg = tid >> 5, ng = tid & 31;
    const int m_off = mg * 8, n_off = ng * 6;

    v2f acc2[4][6];   // rows (2rp, 2rp+1) x col c
    #pragma unroll
    for (int rp = 0; rp < 4; ++rp)
        #pragma unroll
        for (int c = 0; c < 6; ++c) acc2[rp][c] = (v2f){0.f, 0.f};

    for (int kc = 0; kc < K; kc += GEMM_KC) {
        #pragma unroll
        for (int i = 0; i < 2; ++i) {
            int fi = tid + 256 * i;
            int row = fi >> 3, cf = fi & 7;
            int m = mbase + row;
            float4 v = make_float4(0.f, 0.f, 0.f, 0.f);
            if (m < M) v = *(const float4*)&A[(size_t)m * K + kc + cf * 4];
            As[cf * 4 + 0][row] = v.x; As[cf * 4 + 1][row] = v.y;
            As[cf * 4 + 2][row] = v.z; As[cf * 4 + 3][row] = v.w;
        }
        #pragma unroll
        for (int i = 0; i < 6; ++i) {
            int fi = tid + 256 * i;
            int g = fi >> 3, cf = fi & 7;
            const float* Wsel = (g < 96) ? (Wf + (size_t)g * K)
                                         : (Wb + (size_t)(g - 96) * K);
            float4 v = *(const float4*)&Wsel[kc + cf * 4];
            Bs[cf * 4 + 0][g] = v.x; Bs[cf * 4 + 1][g] = v.y;
            Bs[cf * 4 + 2][g] = v.z; Bs[cf * 4 + 3][g] = v.w;
        }
        __syncthreads();
        #pragma unroll
        for (int k = 0; k < GEMM_KC; ++k) {
            float a[8], bb[6];
            *(float4*)&a[0] = *(const float4*)&As[k][m_off];
            *(float4*)&a[4] = *(const float4*)&As[k][m_off + 4];
            *(float2*)&bb[0] = *(const float2*)&Bs[k][n_off];
            *(float2*)&bb[2] = *(const float2*)&Bs[k][n_off + 2];
            *(float2*)&bb[4] = *(const float2*)&Bs[k][n_off + 4];
            #pragma unroll
            for (int rp = 0; rp < 4; ++rp) {
                const v2f av = *(const v2f*)&a[2 * rp];
                #pragma unroll
                for (int c = 0; c < 6; ++c) {
                    const v2f bv = (v2f){bb[c], bb[c]};
                    pk_fma(acc2[rp][c], av, bv);
                }
            }
        }
        __syncthreads();
    }

    float bias[6], gsc[6];
    #pragma unroll
    for (int c = 0; c < 6; ++c) {
        int g = n_off + c;
        int g96 = (g < 96) ? g : g - 96;
        const float* bih = (g < 96) ? bihf : bihb;
        const float* bhh = (g < 96) ? bhhf : bhhb;
        bias[c] = bih[g96] + ((g96 < 64) ? bhh[g96] : 0.f);
        gsc[c]  = (g96 < 64) ? -LOG2E_F : 2.0f * LOG2E_F;
    }
    #pragma unroll
    for (int rp = 0; rp < 4; ++rp) {
        #pragma unroll
        for (int hf = 0; hf < 2; ++hf) {
            int m = mbase + m_off + 2 * rp + hf;
            if (m < M) {
                float* op = &Out[(size_t)m * 192 + n_off];
                #pragma unroll
                for (int c = 0; c < 6; ++c) {
                    const float v = hf ? acc2[rp][c].y : acc2[rp][c].x;
                    op[c] = (v + bias[c]) * gsc[c];
                }
            }
        }
    }
}

// ---------------------------------------------------------------------------
// GRU scan — r8's verified best (146.7 µs/scan), byte-identical revert.
// K-split layout: rows [L,H,L,H]; lane l & l^32 compute complementary
// k-halves of unit j (48 weight VGPRs, pinned); seed via permlane16_swap,
// 15-op DPP butterfly, 24 pk_fma (4+4 split), permlane32 pair-sum combine,
// exp2/rcp gates with log2e pre-folded; 2-step 2-bank gi prefetch; masks
// as per-32-step ballots in SGPRs. r9-r11 structural probes (dual-chain,
// 2-wave co-op) both regressed -> single-wave ~85 instr/step is the floor.
// ---------------------------------------------------------------------------
template <int USE_IDS>
__global__ __launch_bounds__(64, 1)
__attribute__((amdgpu_waves_per_eu(1, 1)))
void gru_scan(
    const float* __restrict__ gi,     // [rows,192]: G0 (gather) or gi1 (direct)
    const int* __restrict__ ids,
    const int* __restrict__ mask,
    const float* __restrict__ Whh_f, const float* __restrict__ Whh_b,
    const float* __restrict__ bhh_f, const float* __restrict__ bhh_b,
    float* __restrict__ out_seq,      // [B,T,64] or nullptr
    float* __restrict__ out_fin)      // [B,64]   or nullptr
{
    const int l = threadIdx.x;
    const int i16 = l & 15;
    const int row = l >> 4;
    const int hi = row & 1;               // unit half
    const int kh = row >> 1;              // k half this lane computes
    const int j = i16 + 16 * hi;          // this lane's unit
    const bool lower = l < 32;            // lanes 0-31: j == l
    const bool self_seed = (hi == kh);    // rows 0,3 own their k-half seed
    const int dir = blockIdx.x & 1;
    const int b = blockIdx.x >> 1;
    const int bT = b * T_;

    const float* Whh = dir ? Whh_b : Whh_f;
    const float* bhh = dir ? bhh_b : bhh_f;

    const float sRZ = -LOG2E_F;
    const float sN2 = 2.0f * LOG2E_F;

    // butterfly value order: pair q holds seed[i16^M0[q]], seed[i16^M1[q]]
    const int M0[8] = {0, 2, 7, 5, 15, 13, 8, 10};
    const int M1[8] = {1, 3, 6, 4, 14, 12, 9, 11};

    v2f wR[8], wZ[8], wN[8];
    #pragma unroll
    for (int q = 0; q < 8; ++q) {
        const int c0 = kh * 16 + (i16 ^ M0[q]);
        const int c1 = kh * 16 + (i16 ^ M1[q]);
        wR[q] = (v2f){Whh[j * 32 + c0] * sRZ, Whh[j * 32 + c1] * sRZ};
        wZ[q] = (v2f){Whh[(32 + j) * 32 + c0] * sRZ,
                      Whh[(32 + j) * 32 + c1] * sRZ};
        wN[q] = (v2f){Whh[(64 + j) * 32 + c0] * sN2,
                      Whh[(64 + j) * 32 + c1] * sN2};
    }
    float bns = bhh[64 + j] * sN2;

    // PIN at init: loads cannot be sunk into the loop.
    #pragma unroll
    for (int q = 0; q < 8; ++q)
        asm volatile("" : "+v"(wR[q]), "+v"(wZ[q]), "+v"(wN[q]));
    asm volatile("" : "+v"(bns));

    const int offR = dir * 96 + j;     // offZ = offR+32, offN = offR+64

    // logical step n = 0..511 maps to time t = dir ? T-1-n : n
    auto t_of = [&](int n) { return dir ? (T_ - 1 - n) : n; };
    // int2 word base for 2-step chunk c
    auto cbase = [&](int c) { return dir ? (bT + 510 - 2 * c) : (bT + 2 * c); };

    // ---- prologue ----
    int mk_cur = lower ? mask[bT + t_of(l)] : 0;
    int mk_nxt = lower ? mask[bT + t_of(32 + l)] : 0;

    int2 ids_pf = make_int2(0, 0), ids_in = make_int2(0, 0);
    float gR[2][2], gZ[2][2], gN[2][2];
    {
        int ra, rb;
        if (USE_IDS) {
            const int2 i0 = *(const int2*)&ids[cbase(0)];
            ra = dir ? i0.y : i0.x;
            rb = dir ? i0.x : i0.y;
            ids_pf = *(const int2*)&ids[cbase(1)];
        } else {
            ra = bT + t_of(0);
            rb = bT + t_of(1);
        }
        const float* ga = gi + (size_t)ra * 192 + offR;
        const float* gb = gi + (size_t)rb * 192 + offR;
        gR[0][0] = ga[0]; gZ[0][0] = ga[32]; gN[0][0] = ga[64];
        gR[0][1] = gb[0]; gZ[0][1] = gb[32]; gN[0][1] = gb[64];
    }

    float h = 0.f;

    for (int seg = 0; seg < 16; ++seg) {
        // keepalive: weights must be arch-VGPR-resident here (16x/kernel)
        #pragma unroll
        for (int q = 0; q < 8; ++q)
            asm volatile("" : "+v"(wR[q]), "+v"(wZ[q]), "+v"(wN[q]));

        const uint32_t mseg = (uint32_t)__ballot(mk_cur != 0);
        mk_cur = mk_nxt;
        {
            const int ms = (seg + 2 < 16) ? (seg + 2) : 15;
            mk_nxt = lower ? mask[bT + t_of(32 * ms + l)] : 0;
        }

        for (int ch2 = 0; ch2 < 8; ++ch2) {
            const int cc0 = seg * 16 + 2 * ch2;
            #pragma unroll
            for (int pb = 0; pb < 2; ++pb) {     // two chunks: banks 0,1
                const int cc = cc0 + pb;
                // ids prefetch for chunk cc+2 (consumed next chunk)
                if (USE_IDS) {
                    const int ci = (cc + 2 < 256) ? (cc + 2) : 255;
                    ids_in = *(const int2*)&ids[cbase(ci)];
                }
                // gi prefetch for chunk cc+1 -> bank pb^1
                {
                    int ra, rb;
                    if (USE_IDS) {
                        ra = dir ? ids_pf.y : ids_pf.x;
                        rb = dir ? ids_pf.x : ids_pf.y;
                    } else {
                        const int cg = (cc + 1 < 256) ? (cc + 1) : 255;
                        ra = bT + t_of(2 * cg);
                        rb = bT + t_of(2 * cg + 1);
                    }
                    const float* ga = gi + (size_t)ra * 192 + offR;
                    const float* gb = gi + (size_t)rb * 192 + offR;
                    gR[pb ^ 1][0] = ga[0]; gZ[pb ^ 1][0] = ga[32]; gN[pb ^ 1][0] = ga[64];
                    gR[pb ^ 1][1] = gb[0]; gZ[pb ^ 1][1] = gb[32]; gN[pb ^ 1][1] = gb[64];
                }

                #pragma unroll
                for (int u = 0; u < 2; ++u) {
                    const int su = 4 * ch2 + 2 * pb + u;   // step within segment

                    // seed = h of (kh*16+i16): rows 0,3 self; rows 1,2 via l^16
                    const float hx = swap16(h);
                    const float seed = self_seed ? h : hx;

                    // distribute 16 seed values within the row (15 DPP movs)
                    v2f p[8];
                    p[0].x = seed;                      p[0].y = mdpp<DPP_XOR1>(seed);
                    p[1].x = mdpp<DPP_XOR2>(seed);      p[1].y = mdpp<DPP_XOR3>(seed);
                    p[2].x = mdpp<DPP_XOR7>(seed);      p[2].y = mdpp<DPP_XOR7>(p[0].y);
                    p[3].x = mdpp<DPP_XOR7>(p[1].x);    p[3].y = mdpp<DPP_XOR7>(p[1].y);
                    p[4].x = mdpp<DPP_XOR15>(seed);     p[4].y = mdpp<DPP_XOR15>(p[0].y);
                    p[5].x = mdpp<DPP_XOR15>(p[1].x);   p[5].y = mdpp<DPP_XOR15>(p[1].y);
                    p[6].x = mdpp<DPP_XOR15>(p[2].x);   p[6].y = mdpp<DPP_XOR15>(p[2].y);
                    p[7].x = mdpp<DPP_XOR15>(p[3].x);   p[7].y = mdpp<DPP_XOR15>(p[3].y);

                    // half-K matvec: 3 gates x (4+4)-split pk_fma chains
                    v2f aR0 = {0.f, 0.f}, aZ0 = {0.f, 0.f}, aN0 = {0.f, 0.f};
                    v2f aR1 = {0.f, 0.f}, aZ1 = {0.f, 0.f}, aN1 = {0.f, 0.f};
                    #pragma unroll
                    for (int q = 0; q < 4; ++q) {
                        pk_fma(aR0, wR[q], p[q]);
                        pk_fma(aZ0, wZ[q], p[q]);
                        pk_fma(aN0, wN[q], p[q]);
                    }
                    #pragma unroll
                    for (int q = 4; q < 8; ++q) {
                        pk_fma(aR1, wR[q], p[q]);
                        pk_fma(aZ1, wZ[q], p[q]);
                        pk_fma(aN1, wN[q], p[q]);
                    }
                    const v2f aR = aR0 + aR1;   // v_pk_add_f32
                    const v2f aZ = aZ0 + aZ1;
                    const v2f aN = aN0 + aN1;

                    // combine k-halves: pair-sum over lanes l, l^32 (same unit)
                    const float SR = xsum32(aR.x + aR.y);
                    const float SZ = xsum32(aZ.x + aZ.y);
                    const float SN = xsum32(aN.x + aN.y);

                    const float yr  = gR[pb][u] + SR;
                    const float yz  = gZ[pb][u] + SZ;
                    const float hns = bns + SN;
                    const float r = rcp_fast(1.0f + exp2_fast(yr));
                    const float z = rcp_fast(1.0f + exp2_fast(yz));
                    const float yn = fmaf(r, hns, gN[pb][u]);
                    const float n = fmaf(-2.0f, rcp_fast(1.0f + exp2_fast(yn)), 1.0f);
                    const float hnew = n + z * (h - n);      // (1-z)n + z h
                    const bool mm = (mseg >> su) & 1u;       // SGPR bit-test
                    h = mm ? hnew : h;                       // packed-seq freeze

                    if (out_seq != nullptr && lower) {
                        const int t = t_of(32 * seg + su);
                        out_seq[(size_t)(bT + t) * 64 + dir * 32 + j] = h;
                    }
                }
                if (USE_IDS) ids_pf = ids_in;   // rotate (1-chunk distance)
            }
        }
    }

    if (out_fin != nullptr && lower)
        out_fin[b * 64 + dir * 32 + j] = h;
}

// ---------------------------------------------------------------------------
// Head: out[b,o] = hfin[b,:] . Wout[o,:] + bout[o]
// ---------------------------------------------------------------------------
__global__ void head_kernel(const float* __restrict__ hfin,
                            const float* __restrict__ Wout,
                            const float* __restrict__ bout,
                            float* __restrict__ out)
{
    int idx = blockIdx.x * blockDim.x + threadIdx.x;
    if (idx >= B_ * 6) return;
    int b = idx / 6, o = idx % 6;
    float acc = bout[o];
    const float* hp = hfin + b * 64;
    const float* wp = Wout + o * 64;
    #pragma unroll
    for (int k = 0; k < 64; ++k) acc = fmaf(hp[k], wp[k], acc);
    out[idx] = acc;
}

// ---------------------------------------------------------------------------
extern "C" void kernel_launch(void* const* d_in, const int* in_sizes, int n_in,
                              void* d_out, int out_size, void* d_ws, size_t ws_size,
                              hipStream_t stream)
{
    const int*   ids   = (const int*)d_in[0];
    const int*   mask  = (const int*)d_in[1];
    const float* embed = (const float*)d_in[2];
    const float* Wih0f = (const float*)d_in[3];
    const float* Whh0f = (const float*)d_in[4];
    const float* bih0f = (const float*)d_in[5];
    const float* bhh0f = (const float*)d_in[6];
    const float* Wih0b = (const float*)d_in[7];
    const float* Whh0b = (const float*)d_in[8];
    const float* bih0b = (const float*)d_in[9];
    const float* bhh0b = (const float*)d_in[10];
    const float* Wih1f = (const float*)d_in[11];
    const float* Whh1f = (const float*)d_in[12];
    const float* bih1f = (const float*)d_in[13];
    const float* bhh1f = (const float*)d_in[14];
    const float* Wih1b = (const float*)d_in[15];
    const float* Whh1b = (const float*)d_in[16];
    const float* bih1b = (const float*)d_in[17];
    const float* bhh1b = (const float*)d_in[18];
    const float* Wout  = (const float*)d_in[19];
    const float* bout  = (const float*)d_in[20];

    // workspace layout (floats):
    //   gbuf : G0 [V,192] (K1,K2) then gi1 [B*T,192] (K3,K4)
    //   x1   : [B,T,64]
    //   hfin : [B,64]
    float* ws   = (float*)d_ws;
    float* gbuf = ws;
    float* x1   = ws + (size_t)B_ * T_ * 192;
    float* hfin = x1 + (size_t)B_ * T_ * 64;

    // K1: vocab-factored layer-0 input gates  G0 = (embed @ Wcat0^T + b) * gsc
    gemm_gates<<<(V_ + GEMM_MT - 1) / GEMM_MT, 256, 0, stream>>>(
        embed, V_, E_, Wih0f, Wih0b, bih0f, bhh0f, bih0b, bhh0b, gbuf);

    // K2: layer-0 bidirectional scan (gathers G0[id]), writes x1
    gru_scan<1><<<2 * B_, 64, 0, stream>>>(
        gbuf, ids, mask, Whh0f, Whh0b, bhh0f, bhh0b, x1, nullptr);

    // K3: layer-1 input gates  gi1 = (x1 @ Wcat1^T + b) * gsc
    gemm_gates<<<(B_ * T_) / GEMM_MT, 256, 0, stream>>>(
        x1, B_ * T_, 64, Wih1f, Wih1b, bih1f, bhh1f, bih1b, bhh1b, gbuf);

    // K4: layer-1 scan, final hiddens only
    gru_scan<0><<<2 * B_, 64, 0, stream>>>(
        gbuf, nullptr, mask, Whh1f, Whh1b, bhh1f, bhh1b, nullptr, hfin);

    // K5: output head
    head_kernel<<<(B_ * 6 + 255) / 256, 256, 0, stream>>>(hfin, Wout, bout,
                                                          (float*)d_out);
}

// Round 13
// 462.649 us; speedup vs baseline: 1.4295x; 1.0037x over previous
//
#include <hip/hip_runtime.h>
#include <hip/hip_bf16.h>
#include <stdint.h>

#define B_ 256
#define T_ 512
#define V_ 30000
#define E_ 256
#define H_ 32

typedef float v2f __attribute__((ext_vector_type(2)));
typedef unsigned int uint2e __attribute__((ext_vector_type(2)));

#define LOG2E_F 1.44269504088896340736f

// ---------------------------------------------------------------------------
// Raw-ISA helpers
// ---------------------------------------------------------------------------
__device__ __forceinline__ float exp2_fast(float x) {      // 2^x
    float r; asm("v_exp_f32 %0, %1" : "=v"(r) : "v"(x)); return r;
}
__device__ __forceinline__ float rcp_fast(float x) {       // 1/x
    float r; asm("v_rcp_f32 %0, %1" : "=v"(r) : "v"(x)); return r;
}
// packed fp32 FMA, all-VGPR operands: acc.{lo,hi} += w.{lo,hi} * h.{lo,hi}
__device__ __forceinline__ void pk_fma(v2f& acc, v2f w, v2f h) {
    asm("v_pk_fma_f32 %0, %1, %2, %0" : "+v"(acc) : "v"(w), "v"(h));
}
// DPP lane-permute move (XOR patterns only -> direction-unambiguous)
template <int CTRL>
__device__ __forceinline__ float mdpp(float x) {
    return __int_as_float(
        __builtin_amdgcn_mov_dpp(__float_as_int(x), CTRL, 0xF, 0xF, true));
}
#define DPP_XOR1  0xB1   // quad_perm [1,0,3,2]
#define DPP_XOR2  0x4E   // quad_perm [2,3,0,1]
#define DPP_XOR3  0x1B   // quad_perm [3,2,1,0]
#define DPP_XOR7  0x141  // row_half_mirror  (i -> i^7 within 8)
#define DPP_XOR15 0x140  // row_mirror       (i -> i^15 within 16)

// x[l] + x[l^32]: permlane32_swap(x,x) yields the pair {x[l], x[l^32]} per
// lane -> sum is exact and order-free (IEEE add commutative).
__device__ __forceinline__ float xsum32(float x) {
    uint2e r = __builtin_amdgcn_permlane32_swap(
        __float_as_uint(x), __float_as_uint(x), false, false);
    return __uint_as_float(r.x) + __uint_as_float(r.y);
}
// value of x at lane (l ^ 16): exact via xor-fold of the {self,swapped} pair
__device__ __forceinline__ float swap16(float x) {
    uint2e r = __builtin_amdgcn_permlane16_swap(
        __float_as_uint(x), __float_as_uint(x), false, false);
    return __uint_as_float(r.x ^ r.y ^ __float_as_uint(x));
}

// ---------------------------------------------------------------------------
// GEMM: Out[M,192] = (A[M,K] @ Wcat[192,K]^T + bias) * gate_scale
// gate_scale folds the exp->exp2 conversion: r,z gates * -log2e ; n * +2log2e
// r13: optional skipm (packed-seq mask over rows). Masks are monotone in t
// within a batch, and M-chunks are 64 consecutive t of one batch -> if
// skipm[mbase]==0 the ENTIRE chunk is padded. Those gi1 rows are only ever
// read by the scan at mm=0 steps where h = select(mm,hnew,h) discards them
// (bitwise select: even NaN garbage is safe) -> block exits, writes nothing.
// ---------------------------------------------------------------------------
#define GEMM_MT 64
#define GEMM_KC 32
#define GEMM_PA 68
#define GEMM_PB 196

__global__ __launch_bounds__(256) void gemm_gates(
    const float* __restrict__ A, int M, int K,
    const float* __restrict__ Wf, const float* __restrict__ Wb,
    const float* __restrict__ bihf, const float* __restrict__ bhhf,
    const float* __restrict__ bihb, const float* __restrict__ bhhb,
    const int* __restrict__ skipm,
    float* __restrict__ Out)
{
    __shared__ float As[GEMM_KC][GEMM_PA];
    __shared__ float Bs[GEMM_KC][GEMM_PB];

    const int tid = threadIdx.x;
    const int mbase = blockIdx.x * GEMM_MT;

    // dead-chunk early exit (see header comment): one scalar load
    if (skipm != nullptr && skipm[mbase] == 0) return;

    const int mg = tid >> 5, ng = tid & 31;
    const int m_off = mg * 8, n_off = ng * 6;

    v2f acc2[4][6];   // rows (2rp, 2rp+1) x col c
    #pragma unroll
    for (int rp = 0; rp < 4; ++rp)
        #pragma unroll
        for (int c = 0; c < 6; ++c) acc2[rp][c] = (v2f){0.f, 0.f};

    for (int kc = 0; kc < K; kc += GEMM_KC) {
        #pragma unroll
        for (int i = 0; i < 2; ++i) {
            int fi = tid + 256 * i;
            int row = fi >> 3, cf = fi & 7;
            int m = mbase + row;
            float4 v = make_float4(0.f, 0.f, 0.f, 0.f);
            if (m < M) v = *(const float4*)&A[(size_t)m * K + kc + cf * 4];
            As[cf * 4 + 0][row] = v.x; As[cf * 4 + 1][row] = v.y;
            As[cf * 4 + 2][row] = v.z; As[cf * 4 + 3][row] = v.w;
        }
        #pragma unroll
        for (int i = 0; i < 6; ++i) {
            int fi = tid + 256 * i;
            int g = fi >> 3, cf = fi & 7;
            const float* Wsel = (g < 96) ? (Wf + (size_t)g * K)
                                         : (Wb + (size_t)(g - 96) * K);
            float4 v = *(const float4*)&Wsel[kc + cf * 4];
            Bs[cf * 4 + 0][g] = v.x; Bs[cf * 4 + 1][g] = v.y;
            Bs[cf * 4 + 2][g] = v.z; Bs[cf * 4 + 3][g] = v.w;
        }
        __syncthreads();
        #pragma unroll
        for (int k = 0; k < GEMM_KC; ++k) {
            float a[8], bb[6];
            *(float4*)&a[0] = *(const float4*)&As[k][m_off];
            *(float4*)&a[4] = *(const float4*)&As[k][m_off + 4];
            *(float2*)&bb[0] = *(const float2*)&Bs[k][n_off];
            *(float2*)&bb[2] = *(const float2*)&Bs[k][n_off + 2];
            *(float2*)&bb[4] = *(const float2*)&Bs[k][n_off + 4];
            #pragma unroll
            for (int rp = 0; rp < 4; ++rp) {
                const v2f av = *(const v2f*)&a[2 * rp];
                #pragma unroll
                for (int c = 0; c < 6; ++c) {
                    const v2f bv = (v2f){bb[c], bb[c]};
                    pk_fma(acc2[rp][c], av, bv);
                }
            }
        }
        __syncthreads();
    }

    float bias[6], gsc[6];
    #pragma unroll
    for (int c = 0; c < 6; ++c) {
        int g = n_off + c;
        int g96 = (g < 96) ? g : g - 96;
        const float* bih = (g < 96) ? bihf : bihb;
        const float* bhh = (g < 96) ? bhhf : bhhb;
        bias[c] = bih[g96] + ((g96 < 64) ? bhh[g96] : 0.f);
        gsc[c]  = (g96 < 64) ? -LOG2E_F : 2.0f * LOG2E_F;
    }
    #pragma unroll
    for (int rp = 0; rp < 4; ++rp) {
        #pragma unroll
        for (int hf = 0; hf < 2; ++hf) {
            int m = mbase + m_off + 2 * rp + hf;
            if (m < M) {
                float* op = &Out[(size_t)m * 192 + n_off];
                #pragma unroll
                for (int c = 0; c < 6; ++c) {
                    const float v = hf ? acc2[rp][c].y : acc2[rp][c].x;
                    op[c] = (v + bias[c]) * gsc[c];
                }
            }
        }
    }
}

// ---------------------------------------------------------------------------
// GRU scan — r8's verified best (146.7 µs/scan). Only r13 change: out_seq
// store is skipped at masked steps (mm wave-uniform -> s_cbranch). x1 rows
// at padded t are then garbage — provably never consumed: K3 dead-chunks
// exit, live chunks' garbage rows produce garbage gi1 rows read only at
// mm=0 steps where the bitwise select discards them.
// K-split layout: rows [L,H,L,H]; lane l & l^32 compute complementary
// k-halves of unit j (48 weight VGPRs, pinned); seed via permlane16_swap,
// 15-op DPP butterfly, 24 pk_fma (4+4 split), permlane32 pair-sum combine,
// exp2/rcp gates with log2e pre-folded; 2-step 2-bank gi prefetch; masks
// as per-32-step ballots in SGPRs. r9-r11 structural probes (dual-chain,
// 2-wave co-op) both regressed -> single-wave ~85 instr/step is the floor.
// ---------------------------------------------------------------------------
template <int USE_IDS>
__global__ __launch_bounds__(64, 1)
__attribute__((amdgpu_waves_per_eu(1, 1)))
void gru_scan(
    const float* __restrict__ gi,     // [rows,192]: G0 (gather) or gi1 (direct)
    const int* __restrict__ ids,
    const int* __restrict__ mask,
    const float* __restrict__ Whh_f, const float* __restrict__ Whh_b,
    const float* __restrict__ bhh_f, const float* __restrict__ bhh_b,
    float* __restrict__ out_seq,      // [B,T,64] or nullptr
    float* __restrict__ out_fin)      // [B,64]   or nullptr
{
    const int l = threadIdx.x;
    const int i16 = l & 15;
    const int row = l >> 4;
    const int hi = row & 1;               // unit half
    const int kh = row >> 1;              // k half this lane computes
    const int j = i16 + 16 * hi;          // this lane's unit
    const bool lower = l < 32;            // lanes 0-31: j == l
    const bool self_seed = (hi == kh);    // rows 0,3 own their k-half seed
    const int dir = blockIdx.x & 1;
    const int b = blockIdx.x >> 1;
    const int bT = b * T_;

    const float* Whh = dir ? Whh_b : Whh_f;
    const float* bhh = dir ? bhh_b : bhh_f;

    const float sRZ = -LOG2E_F;
    const float sN2 = 2.0f * LOG2E_F;

    // butterfly value order: pair q holds seed[i16^M0[q]], seed[i16^M1[q]]
    const int M0[8] = {0, 2, 7, 5, 15, 13, 8, 10};
    const int M1[8] = {1, 3, 6, 4, 14, 12, 9, 11};

    v2f wR[8], wZ[8], wN[8];
    #pragma unroll
    for (int q = 0; q < 8; ++q) {
        const int c0 = kh * 16 + (i16 ^ M0[q]);
        const int c1 = kh * 16 + (i16 ^ M1[q]);
        wR[q] = (v2f){Whh[j * 32 + c0] * sRZ, Whh[j * 32 + c1] * sRZ};
        wZ[q] = (v2f){Whh[(32 + j) * 32 + c0] * sRZ,
                      Whh[(32 + j) * 32 + c1] * sRZ};
        wN[q] = (v2f){Whh[(64 + j) * 32 + c0] * sN2,
                      Whh[(64 + j) * 32 + c1] * sN2};
    }
    float bns = bhh[64 + j] * sN2;

    // PIN at init: loads cannot be sunk into the loop.
    #pragma unroll
    for (int q = 0; q < 8; ++q)
        asm volatile("" : "+v"(wR[q]), "+v"(wZ[q]), "+v"(wN[q]));
    asm volatile("" : "+v"(bns));

    const int offR = dir * 96 + j;     // offZ = offR+32, offN = offR+64

    // logical step n = 0..511 maps to time t = dir ? T-1-n : n
    auto t_of = [&](int n) { return dir ? (T_ - 1 - n) : n; };
    // int2 word base for 2-step chunk c
    auto cbase = [&](int c) { return dir ? (bT + 510 - 2 * c) : (bT + 2 * c); };

    // ---- prologue ----
    int mk_cur = lower ? mask[bT + t_of(l)] : 0;
    int mk_nxt = lower ? mask[bT + t_of(32 + l)] : 0;

    int2 ids_pf = make_int2(0, 0), ids_in = make_int2(0, 0);
    float gR[2][2], gZ[2][2], gN[2][2];
    {
        int ra, rb;
        if (USE_IDS) {
            const int2 i0 = *(const int2*)&ids[cbase(0)];
            ra = dir ? i0.y : i0.x;
            rb = dir ? i0.x : i0.y;
            ids_pf = *(const int2*)&ids[cbase(1)];
        } else {
            ra = bT + t_of(0);
            rb = bT + t_of(1);
        }
        const float* ga = gi + (size_t)ra * 192 + offR;
        const float* gb = gi + (size_t)rb * 192 + offR;
        gR[0][0] = ga[0]; gZ[0][0] = ga[32]; gN[0][0] = ga[64];
        gR[0][1] = gb[0]; gZ[0][1] = gb[32]; gN[0][1] = gb[64];
    }

    float h = 0.f;

    for (int seg = 0; seg < 16; ++seg) {
        // keepalive: weights must be arch-VGPR-resident here (16x/kernel)
        #pragma unroll
        for (int q = 0; q < 8; ++q)
            asm volatile("" : "+v"(wR[q]), "+v"(wZ[q]), "+v"(wN[q]));

        const uint32_t mseg = (uint32_t)__ballot(mk_cur != 0);
        mk_cur = mk_nxt;
        {
            const int ms = (seg + 2 < 16) ? (seg + 2) : 15;
            mk_nxt = lower ? mask[bT + t_of(32 * ms + l)] : 0;
        }

        for (int ch2 = 0; ch2 < 8; ++ch2) {
            const int cc0 = seg * 16 + 2 * ch2;
            #pragma unroll
            for (int pb = 0; pb < 2; ++pb) {     // two chunks: banks 0,1
                const int cc = cc0 + pb;
                // ids prefetch for chunk cc+2 (consumed next chunk)
                if (USE_IDS) {
                    const int ci = (cc + 2 < 256) ? (cc + 2) : 255;
                    ids_in = *(const int2*)&ids[cbase(ci)];
                }
                // gi prefetch for chunk cc+1 -> bank pb^1
                {
                    int ra, rb;
                    if (USE_IDS) {
                        ra = dir ? ids_pf.y : ids_pf.x;
                        rb = dir ? ids_pf.x : ids_pf.y;
                    } else {
                        const int cg = (cc + 1 < 256) ? (cc + 1) : 255;
                        ra = bT + t_of(2 * cg);
                        rb = bT + t_of(2 * cg + 1);
                    }
                    const float* ga = gi + (size_t)ra * 192 + offR;
                    const float* gb = gi + (size_t)rb * 192 + offR;
                    gR[pb ^ 1][0] = ga[0]; gZ[pb ^ 1][0] = ga[32]; gN[pb ^ 1][0] = ga[64];
                    gR[pb ^ 1][1] = gb[0]; gZ[pb ^ 1][1] = gb[32]; gN[pb ^ 1][1] = gb[64];
                }

                #pragma unroll
                for (int u = 0; u < 2; ++u) {
                    const int su = 4 * ch2 + 2 * pb + u;   // step within segment

                    // seed = h of (kh*16+i16): rows 0,3 self; rows 1,2 via l^16
                    const float hx = swap16(h);
                    const float seed = self_seed ? h : hx;

                    // distribute 16 seed values within the row (15 DPP movs)
                    v2f p[8];
                    p[0].x = seed;                      p[0].y = mdpp<DPP_XOR1>(seed);
                    p[1].x = mdpp<DPP_XOR2>(seed);      p[1].y = mdpp<DPP_XOR3>(seed);
                    p[2].x = mdpp<DPP_XOR7>(seed);      p[2].y = mdpp<DPP_XOR7>(p[0].y);
                    p[3].x = mdpp<DPP_XOR7>(p[1].x);    p[3].y = mdpp<DPP_XOR7>(p[1].y);
                    p[4].x = mdpp<DPP_XOR15>(seed);     p[4].y = mdpp<DPP_XOR15>(p[0].y);
                    p[5].x = mdpp<DPP_XOR15>(p[1].x);   p[5].y = mdpp<DPP_XOR15>(p[1].y);
                    p[6].x = mdpp<DPP_XOR15>(p[2].x);   p[6].y = mdpp<DPP_XOR15>(p[2].y);
                    p[7].x = mdpp<DPP_XOR15>(p[3].x);   p[7].y = mdpp<DPP_XOR15>(p[3].y);

                    // half-K matvec: 3 gates x (4+4)-split pk_fma chains
                    v2f aR0 = {0.f, 0.f}, aZ0 = {0.f, 0.f}, aN0 = {0.f, 0.f};
                    v2f aR1 = {0.f, 0.f}, aZ1 = {0.f, 0.f}, aN1 = {0.f, 0.f};
                    #pragma unroll
                    for (int q = 0; q < 4; ++q) {
                        pk_fma(aR0, wR[q], p[q]);
                        pk_fma(aZ0, wZ[q], p[q]);
                        pk_fma(aN0, wN[q], p[q]);
                    }
                    #pragma unroll
                    for (int q = 4; q < 8; ++q) {
                        pk_fma(aR1, wR[q], p[q]);
                        pk_fma(aZ1, wZ[q], p[q]);
                        pk_fma(aN1, wN[q], p[q]);
                    }
                    const v2f aR = aR0 + aR1;   // v_pk_add_f32
                    const v2f aZ = aZ0 + aZ1;
                    const v2f aN = aN0 + aN1;

                    // combine k-halves: pair-sum over lanes l, l^32 (same unit)
                    const float SR = xsum32(aR.x + aR.y);
                    const float SZ = xsum32(aZ.x + aZ.y);
                    const float SN = xsum32(aN.x + aN.y);

                    const float yr  = gR[pb][u] + SR;
                    const float yz  = gZ[pb][u] + SZ;
                    const float hns = bns + SN;
                    const float r = rcp_fast(1.0f + exp2_fast(yr));
                    const float z = rcp_fast(1.0f + exp2_fast(yz));
                    const float yn = fmaf(r, hns, gN[pb][u]);
                    const float n = fmaf(-2.0f, rcp_fast(1.0f + exp2_fast(yn)), 1.0f);
                    const float hnew = n + z * (h - n);      // (1-z)n + z h
                    const bool mm = (mseg >> su) & 1u;       // SGPR bit-test
                    h = mm ? hnew : h;                       // packed-seq freeze

                    // store only at live steps (mm wave-uniform -> s_cbranch);
                    // padded x1 rows stay garbage — never consumed (see K3)
                    if (out_seq != nullptr && mm && lower) {
                        const int t = t_of(32 * seg + su);
                        out_seq[(size_t)(bT + t) * 64 + dir * 32 + j] = h;
                    }
                }
                if (USE_IDS) ids_pf = ids_in;   // rotate (1-chunk distance)
            }
        }
    }

    if (out_fin != nullptr && lower)
        out_fin[b * 64 + dir * 32 + j] = h;
}

// ---------------------------------------------------------------------------
// Head: out[b,o] = hfin[b,:] . Wout[o,:] + bout[o]
// ---------------------------------------------------------------------------
__global__ void head_kernel(const float* __restrict__ hfin,
                            const float* __restrict__ Wout,
                            const float* __restrict__ bout,
                            float* __restrict__ out)
{
    int idx = blockIdx.x * blockDim.x + threadIdx.x;
    if (idx >= B_ * 6) return;
    int b = idx / 6, o = idx % 6;
    float acc = bout[o];
    const float* hp = hfin + b * 64;
    const float* wp = Wout + o * 64;
    #pragma unroll
    for (int k = 0; k < 64; ++k) acc = fmaf(hp[k], wp[k], acc);
    out[idx] = acc;
}

// ---------------------------------------------------------------------------
extern "C" void kernel_launch(void* const* d_in, const int* in_sizes, int n_in,
                              void* d_out, int out_size, void* d_ws, size_t ws_size,
                              hipStream_t stream)
{
    const int*   ids   = (const int*)d_in[0];
    const int*   mask  = (const int*)d_in[1];
    const float* embed = (const float*)d_in[2];
    const float* Wih0f = (const float*)d_in[3];
    const float* Whh0f = (const float*)d_in[4];
    const float* bih0f = (const float*)d_in[5];
    const float* bhh0f = (const float*)d_in[6];
    const float* Wih0b = (const float*)d_in[7];
    const float* Whh0b = (const float*)d_in[8];
    const float* bih0b = (const float*)d_in[9];
    const float* bhh0b = (const float*)d_in[10];
    const float* Wih1f = (const float*)d_in[11];
    const float* Whh1f = (const float*)d_in[12];
    const float* bih1f = (const float*)d_in[13];
    const float* bhh1f = (const float*)d_in[14];
    const float* Wih1b = (const float*)d_in[15];
    const float* Whh1b = (const float*)d_in[16];
    const float* bih1b = (const float*)d_in[17];
    const float* bhh1b = (const float*)d_in[18];
    const float* Wout  = (const float*)d_in[19];
    const float* bout  = (const float*)d_in[20];

    // workspace layout (floats):
    //   gbuf : G0 [V,192] (K1,K2) then gi1 [B*T,192] (K3,K4)
    //   x1   : [B,T,64]
    //   hfin : [B,64]
    float* ws   = (float*)d_ws;
    float* gbuf = ws;
    float* x1   = ws + (size_t)B_ * T_ * 192;
    float* hfin = x1 + (size_t)B_ * T_ * 64;

    // K1: vocab-factored layer-0 input gates  G0 = (embed @ Wcat0^T + b) * gsc
    gemm_gates<<<(V_ + GEMM_MT - 1) / GEMM_MT, 256, 0, stream>>>(
        embed, V_, E_, Wih0f, Wih0b, bih0f, bhh0f, bih0b, bhh0b,
        nullptr, gbuf);

    // K2: layer-0 bidirectional scan (gathers G0[id]), writes x1 (live t only)
    gru_scan<1><<<2 * B_, 64, 0, stream>>>(
        gbuf, ids, mask, Whh0f, Whh0b, bhh0f, bhh0b, x1, nullptr);

    // K3: layer-1 input gates  gi1 = (x1 @ Wcat1^T + b) * gsc
    //     dead 64-row chunks (fully padded) exit via skipm
    gemm_gates<<<(B_ * T_) / GEMM_MT, 256, 0, stream>>>(
        x1, B_ * T_, 64, Wih1f, Wih1b, bih1f, bhh1f, bih1b, bhh1b,
        mask, gbuf);

    // K4: layer-1 scan, final hiddens only
    gru_scan<0><<<2 * B_, 64, 0, stream>>>(
        gbuf, nullptr, mask, Whh1f, Whh1b, bhh1f, bhh1b, nullptr, hfin);

    // K5: output head
    head_kernel<<<(B_ * 6 + 255) / 256, 256, 0, stream>>>(hfin, Wout, bout,
                                                          (float*)d_out);
}